// Round 7
// baseline (630.722 us; speedup 1.0000x reference)
//
#include <hip/hip_runtime.h>

#define N_NODES 50000
#define N_EDGES 800000
#define DIM 128
#define KTOT 256        // [agg | x] concatenated along k
#define N_GRAPHS 64
#define P_BLOCKS 512
#define LSTR 264        // LDS A-tile row stride in bf16 (+8 pad -> conflict-free b128)
#define SCAN_T 1024
#define PER_T ((N_NODES + SCAN_T - 1) / SCAN_T)   // 49

typedef __attribute__((ext_vector_type(8))) short bf16x8;
typedef __attribute__((ext_vector_type(16))) float f32x16;

__device__ __forceinline__ float bf2f(unsigned int u16) {
    return __uint_as_float(u16 << 16);
}
__device__ __forceinline__ unsigned short f2bf(float f) {
    unsigned int v = __float_as_uint(f);
    unsigned int r = (v + 0x7fffu + ((v >> 16) & 1u)) >> 16;   // RNE
    return (unsigned short)r;
}

// ---------- setup: degree -> scan -> CSR fill ----------
// castx also zeros cnt (must precede deg_kernel)
__global__ void castx_kernel(const float* __restrict__ x, ushort* __restrict__ xb,
                             int* __restrict__ cnt) {
    int i = blockIdx.x * blockDim.x + threadIdx.x;
    if (i < N_NODES) cnt[i] = 0;
    if (i >= N_NODES * DIM / 4) return;
    float4 v = ((const float4*)x)[i];
    ushort4 o;
    o.x = f2bf(v.x); o.y = f2bf(v.y); o.z = f2bf(v.z); o.w = f2bf(v.w);
    ((ushort4*)xb)[i] = o;
}

__global__ void castw_kernel(const float* __restrict__ Wl0, const float* __restrict__ Wr0,
                             const float* __restrict__ Wl1, const float* __restrict__ Wr1,
                             const float* __restrict__ Wl2, const float* __restrict__ Wr2,
                             ushort* __restrict__ wb, float* __restrict__ pool) {
    int id = blockIdx.x * blockDim.x + threadIdx.x;
    if (id < N_GRAPHS * DIM) pool[id] = 0.f;
    if (id >= 3 * DIM * KTOT) return;
    int l = id >> 15;
    int r = id & 32767;
    int j = r >> 8, k = r & 255;
    const float* Wl = (l == 0) ? Wl0 : (l == 1) ? Wl1 : Wl2;
    const float* Wr = (l == 0) ? Wr0 : (l == 1) ? Wr1 : Wr2;
    float v = (k < DIM) ? Wl[j * DIM + k] : Wr[j * DIM + k - DIM];
    wb[id] = f2bf(v);
}

__global__ void deg_kernel(const int* __restrict__ dst, int* __restrict__ cnt) {
    int e = blockIdx.x * blockDim.x + threadIdx.x;
    if (e < N_EDGES) atomicAdd(&cnt[dst[e]], 1);
}

// Single-block exclusive scan: rowptr[0..N] and a cursor copy for the fill.
__global__ __launch_bounds__(SCAN_T) void scan_kernel(const int* __restrict__ cnt,
                                                      int* __restrict__ rowptr,
                                                      int* __restrict__ cursor) {
    __shared__ int part[SCAN_T];
    int t = threadIdx.x;
    int base = t * PER_T;
    int s = 0;
    for (int i = 0; i < PER_T; ++i) {
        int n = base + i;
        if (n < N_NODES) s += cnt[n];
    }
    part[t] = s;
    __syncthreads();
    for (int off = 1; off < SCAN_T; off <<= 1) {
        int add = (t >= off) ? part[t - off] : 0;
        __syncthreads();
        part[t] += add;
        __syncthreads();
    }
    int run = part[t] - s;       // exclusive prefix for this thread's range
    for (int i = 0; i < PER_T; ++i) {
        int n = base + i;
        if (n < N_NODES) {
            rowptr[n] = run;
            cursor[n] = run;
            run += cnt[n];
        }
    }
    if (t == SCAN_T - 1) rowptr[N_NODES] = N_EDGES;
}

// Compact CSR fill: scatter target is 1.6 MB -> L2-resident, minimal writeback.
__global__ void fillcsr_kernel(const int* __restrict__ src, const int* __restrict__ dst,
                               int* __restrict__ cursor, ushort* __restrict__ csr) {
    int e = blockIdx.x * blockDim.x + threadIdx.x;
    if (e >= N_EDGES) return;
    int pos = atomicAdd(&cursor[dst[e]], 1);
    csr[pos] = (ushort)src[e];
}

// ---------- pull aggregation, column-segmented for L2 residency ----------
// grid.y = 4 column passes; pass touches a 3.2 MB line-slice of X (fits XCD L2).
// Wave: sub = lane>>4 owns edge slot (4 edges/load-instr), lcol = lane&15 owns
// a uint (2 bf16 cols) of the 64 B segment. 4-deep unroll = 16 rows in flight.
__global__ __launch_bounds__(256) void gather_kernel(
    const ushort* __restrict__ X, const int* __restrict__ rowptr,
    const ushort* __restrict__ csr, ushort* __restrict__ agg) {
    int n = (blockIdx.x * blockDim.x + threadIdx.x) >> 6;
    if (n >= N_NODES) return;
    const int lane = threadIdx.x & 63;
    const int sub = lane >> 4;
    const int lcol = lane & 15;
    const int coff = blockIdx.y * 32 + lcol * 2;
    const int rs = rowptr[n], re = rowptr[n + 1];
    const int deg = re - rs;
    float ax = 0.f, ay = 0.f;
    int e = rs + sub;
    for (; e + 12 < re; e += 16) {
        int s0 = csr[e], s1 = csr[e + 4], s2 = csr[e + 8], s3 = csr[e + 12];
        unsigned int u0 = *(const unsigned int*)(X + (size_t)s0 * DIM + coff);
        unsigned int u1 = *(const unsigned int*)(X + (size_t)s1 * DIM + coff);
        unsigned int u2 = *(const unsigned int*)(X + (size_t)s2 * DIM + coff);
        unsigned int u3 = *(const unsigned int*)(X + (size_t)s3 * DIM + coff);
        ax += bf2f(u0 & 0xffff) + bf2f(u1 & 0xffff) + bf2f(u2 & 0xffff) + bf2f(u3 & 0xffff);
        ay += bf2f(u0 >> 16)    + bf2f(u1 >> 16)    + bf2f(u2 >> 16)    + bf2f(u3 >> 16);
    }
    for (; e < re; e += 4) {
        unsigned int u0 = *(const unsigned int*)(X + (size_t)csr[e] * DIM + coff);
        ax += bf2f(u0 & 0xffff);
        ay += bf2f(u0 >> 16);
    }
    ax += __shfl_xor(ax, 16); ax += __shfl_xor(ax, 32);
    ay += __shfl_xor(ay, 16); ay += __shfl_xor(ay, 32);
    if (lane < 16) {
        float inv = 1.0f / (float)(deg > 0 ? deg : 1);
        unsigned int o = ((unsigned int)f2bf(ay * inv) << 16) | f2bf(ax * inv);
        *(unsigned int*)(agg + (size_t)n * DIM + coff) = o;
    }
}

// ---------- MFMA layer: out[50000x128] = [agg|h][50000x256] . W[128x256]^T ----------
__global__ __launch_bounds__(512, 4) void layer_mfma(
    const ushort* __restrict__ aggb, const ushort* __restrict__ hb,
    const ushort* __restrict__ wb, const float* __restrict__ bl,
    ushort* __restrict__ outb, int relu)
{
    __shared__ ushort sA[64 * LSTR];
    const int tid = threadIdx.x;
    const int lane = tid & 63, w = tid >> 6;
    const int mh = w & 1, jq = w >> 1;
    const int n0 = blockIdx.x * 64;

    bf16x8 bw[16];
    {
        const ushort* wp = wb + (size_t)(jq * 32 + (lane & 31)) * KTOT + (lane >> 5) * 8;
        #pragma unroll
        for (int kt = 0; kt < 16; ++kt)
            bw[kt] = *(const bf16x8*)(wp + kt * 16);
    }

    #pragma unroll
    for (int it = 0; it < 4; ++it) {
        int ci = tid + it * 512;
        int row = ci >> 5;
        int k8 = (ci & 31) * 8;
        int gn = n0 + row;
        bf16x8 v = (bf16x8){0,0,0,0,0,0,0,0};
        if (gn < N_NODES) {
            const ushort* p = (k8 < DIM) ? (aggb + (size_t)gn * DIM + k8)
                                         : (hb + (size_t)gn * DIM + (k8 - DIM));
            v = *(const bf16x8*)p;
        }
        *(bf16x8*)(&sA[row * LSTR + k8]) = v;
    }
    __syncthreads();

    f32x16 acc = {};
    const int arow = mh * 32 + (lane & 31);
    const int akoff = (lane >> 5) * 8;
    #pragma unroll
    for (int kt = 0; kt < 16; ++kt) {
        bf16x8 a = *(const bf16x8*)(&sA[arow * LSTR + kt * 16 + akoff]);
        acc = __builtin_amdgcn_mfma_f32_32x32x16_bf16(a, bw[kt], acc, 0, 0, 0);
    }

    // C/D map: col=lane&31, row=(reg&3)+8*(reg>>2)+4*(lane>>5)  [m74/m101]
    const int col = lane & 31;
    const int j = jq * 32 + col;
    const float bias = bl[j];
    #pragma unroll
    for (int r = 0; r < 16; ++r) {
        int row = (r & 3) + 8 * (r >> 2) + 4 * (lane >> 5);
        int gn = n0 + mh * 32 + row;
        if (gn < N_NODES) {
            float v = acc[r] + bias;
            if (relu) v = fmaxf(v, 0.f);
            outb[(size_t)gn * DIM + j] = f2bf(v);
        }
    }
}

// ---------- pool ----------
__global__ void pool1_kernel(const ushort* __restrict__ H, const int* __restrict__ batch,
                             float* __restrict__ pool) {
    const int per = (N_NODES + P_BLOCKS - 1) / P_BLOCKS;
    int n0 = blockIdx.x * per;
    int n1 = n0 + per; if (n1 > N_NODES) n1 = N_NODES;
    if (n0 >= n1) return;
    int j = threadIdx.x;
    float acc = 0.f;
    int g = batch[n0];
    for (int n = n0; n < n1; ++n) {
        int bg = batch[n];
        if (bg != g) {
            unsafeAtomicAdd(&pool[g * DIM + j], acc);
            acc = 0.f; g = bg;
        }
        acc += bf2f(H[(size_t)n * DIM + j]);
    }
    unsafeAtomicAdd(&pool[g * DIM + j], acc);
}

__global__ void pool2_kernel(const float* __restrict__ pool, const int* __restrict__ batch,
                             float* __restrict__ out) {
    int g = blockIdx.x;
    int j = threadIdx.x;
    int lo = 0, hi = N_NODES;
    while (lo < hi) { int m = (lo + hi) >> 1; if (batch[m] < g) lo = m + 1; else hi = m; }
    int start = lo;
    lo = start; hi = N_NODES;
    while (lo < hi) { int m = (lo + hi) >> 1; if (batch[m] < g + 1) lo = m + 1; else hi = m; }
    int cnt = lo - start;
    out[g * DIM + j] = pool[g * DIM + j] / (float)(cnt > 0 ? cnt : 1);
}

extern "C" void kernel_launch(void* const* d_in, const int* in_sizes, int n_in,
                              void* d_out, int out_size, void* d_ws, size_t ws_size,
                              hipStream_t stream) {
    const float* x    = (const float*)d_in[0];
    const int*   ei   = (const int*)d_in[1];
    const int*   src  = ei;
    const int*   dst  = ei + N_EDGES;
    const int*   batch = (const int*)d_in[2];
    const float* Wl0 = (const float*)d_in[3];
    const float* bl0 = (const float*)d_in[4];
    const float* Wr0 = (const float*)d_in[5];
    const float* Wl1 = (const float*)d_in[6];
    const float* bl1 = (const float*)d_in[7];
    const float* Wr1 = (const float*)d_in[8];
    const float* Wl2 = (const float*)d_in[9];
    const float* bl2 = (const float*)d_in[10];
    const float* Wr2 = (const float*)d_in[11];
    float* out = (float*)d_out;

    int*    cnt    = (int*)d_ws;                               // 65536 ints
    int*    rowptr = cnt + 65536;                              // 65536 ints
    int*    cursor = rowptr + 65536;                           // 65536 ints
    ushort* csr    = (ushort*)(cursor + 65536);                // 800k ushorts (pad to 1M)
    ushort* xb     = csr + 1048576;
    ushort* aggb   = xb + (size_t)N_NODES * DIM;
    ushort* h1b    = aggb + (size_t)N_NODES * DIM;
    ushort* h2b    = h1b + (size_t)N_NODES * DIM;
    ushort* h3b    = h2b + (size_t)N_NODES * DIM;
    ushort* wb     = h3b + (size_t)N_NODES * DIM;              // 3 * 32768 bf16
    float*  pool   = (float*)(wb + 3 * DIM * KTOT);            // 8192 floats

    castx_kernel<<<(N_NODES * DIM / 4 + 255) / 256, 256, 0, stream>>>(x, xb, cnt);
    castw_kernel<<<(3 * DIM * KTOT + 255) / 256, 256, 0, stream>>>(Wl0, Wr0, Wl1, Wr1, Wl2, Wr2, wb, pool);
    deg_kernel<<<(N_EDGES + 255) / 256, 256, 0, stream>>>(dst, cnt);
    scan_kernel<<<1, SCAN_T, 0, stream>>>(cnt, rowptr, cursor);
    fillcsr_kernel<<<(N_EDGES + 255) / 256, 256, 0, stream>>>(src, dst, cursor, csr);

    dim3 ggrid((N_NODES + 3) / 4, 4);
    const int lgrid = (N_NODES + 63) / 64;

    gather_kernel<<<ggrid, 256, 0, stream>>>(xb, rowptr, csr, aggb);
    layer_mfma<<<lgrid, 512, 0, stream>>>(aggb, xb, wb,          bl0, h1b, 1);
    gather_kernel<<<ggrid, 256, 0, stream>>>(h1b, rowptr, csr, aggb);
    layer_mfma<<<lgrid, 512, 0, stream>>>(aggb, h1b, wb + 32768, bl1, h2b, 1);
    gather_kernel<<<ggrid, 256, 0, stream>>>(h2b, rowptr, csr, aggb);
    layer_mfma<<<lgrid, 512, 0, stream>>>(aggb, h2b, wb + 65536, bl2, h3b, 0);

    pool1_kernel<<<P_BLOCKS, DIM, 0, stream>>>(h3b, batch, pool);
    pool2_kernel<<<N_GRAPHS, DIM, 0, stream>>>(pool, batch, out);
}

// Round 8
// 386.890 us; speedup vs baseline: 1.6302x; 1.6302x over previous
//
#include <hip/hip_runtime.h>

#define N_NODES 50000
#define N_EDGES 800000
#define DIM 128
#define KTOT 256        // [agg | h] concatenated along k
#define N_GRAPHS 64
#define BUCKET_CAP 64
#define P_BLOCKS 512
#define LSTR 264        // LDS A-tile row stride in bf16 (+8 pad -> conflict-free b128)

typedef __attribute__((ext_vector_type(8))) short bf16x8;
typedef __attribute__((ext_vector_type(16))) float f32x16;

__device__ __forceinline__ float bf2f(unsigned int u16) {
    return __uint_as_float(u16 << 16);
}
__device__ __forceinline__ unsigned short f2bf(float f) {
    unsigned int v = __float_as_uint(f);
    unsigned int r = (v + 0x7fffu + ((v >> 16) & 1u)) >> 16;   // RNE
    return (unsigned short)r;
}

// ---------- setup ----------
// castx also zeros cnt (must precede fill_kernel)
__global__ void castx_kernel(const float* __restrict__ x, ushort* __restrict__ xb,
                             int* __restrict__ cnt) {
    int i = blockIdx.x * blockDim.x + threadIdx.x;
    if (i < N_NODES) cnt[i] = 0;
    if (i >= N_NODES * DIM / 4) return;
    float4 v = ((const float4*)x)[i];
    ushort4 o;
    o.x = f2bf(v.x); o.y = f2bf(v.y); o.z = f2bf(v.z); o.w = f2bf(v.w);
    ((ushort4*)xb)[i] = o;
}

// wb layout per layer: [128 j][256 k] with k<128 = Wl, k>=128 = Wr. Also zeros pool.
__global__ void castw_kernel(const float* __restrict__ Wl0, const float* __restrict__ Wr0,
                             const float* __restrict__ Wl1, const float* __restrict__ Wr1,
                             const float* __restrict__ Wl2, const float* __restrict__ Wr2,
                             ushort* __restrict__ wb, float* __restrict__ pool) {
    int id = blockIdx.x * blockDim.x + threadIdx.x;
    if (id < N_GRAPHS * DIM) pool[id] = 0.f;
    if (id >= 3 * DIM * KTOT) return;
    int l = id >> 15;
    int r = id & 32767;
    int j = r >> 8, k = r & 255;
    const float* Wl = (l == 0) ? Wl0 : (l == 1) ? Wl1 : Wl2;
    const float* Wr = (l == 0) ? Wr0 : (l == 1) ? Wr1 : Wr2;
    float v = (k < DIM) ? Wl[j * DIM + k] : Wr[j * DIM + k - DIM];
    wb[id] = f2bf(v);
}

// ushort buckets: src < 50000 fits 16 bits (R6-proven; CSR+scan regressed in R7).
__global__ void fill_kernel(const int* __restrict__ src, const int* __restrict__ dst,
                            int* __restrict__ cnt, ushort* __restrict__ bucket) {
    int e = blockIdx.x * blockDim.x + threadIdx.x;
    if (e >= N_EDGES) return;
    int d = dst[e];
    int pos = atomicAdd(&cnt[d], 1);
    if (pos < BUCKET_CAP) bucket[d * BUCKET_CAP + pos] = (ushort)src[e];
}

// ---------- fused layer: gather (mean-agg into LDS) + MFMA GEMM ----------
// out[n][:] = act( [mean_agg(X)[n] | X[n]] @ W^T + bl ),  W = [Wl|Wr] 128x256.
// 512 thr = 8 waves, 64 nodes/block. Gather phase: wave w owns rows w*8..w*8+7;
// half-wave = one 256B edge row per load instr, 4-deep unroll (8 rows in flight),
// shfl_xor(32) combine, lanes<32 write the row into sA[k<128]. h-part (k>=128)
// staged from the same X. Then 16x MFMA 32x32x16 with W fragments in VGPRs.
__global__ __launch_bounds__(512, 2) void layer_fused(
    const ushort* __restrict__ X, const ushort* __restrict__ wb,
    const float* __restrict__ bl, const int* __restrict__ cnt,
    const ushort* __restrict__ bucket, ushort* __restrict__ outb, int relu)
{
    __shared__ ushort sA[64 * LSTR];
    const int tid = threadIdx.x;
    const int lane = tid & 63, w = tid >> 6;
    const int n0 = blockIdx.x * 64;

    // ---- gather phase ----
    {
        const int half = lane >> 5;      // 0/1: even/odd edges
        const int lcol = lane & 31;      // 4 cols (8 B) of the 256 B row
        for (int i = 0; i < 8; ++i) {
            int row = w * 8 + i;
            int gn = n0 + row;
            float a0 = 0.f, a1 = 0.f, a2 = 0.f, a3 = 0.f;
            int c = 0;
            if (gn < N_NODES) {
                c = cnt[gn];
                int cl = c < BUCKET_CAP ? c : BUCKET_CAP;
                const ushort* b = bucket + (size_t)gn * BUCKET_CAP;
                int e = half;
                for (; e + 6 < cl; e += 8) {
                    int s0 = b[e], s1 = b[e + 2], s2 = b[e + 4], s3 = b[e + 6];
                    uint2 u0 = *(const uint2*)(X + (size_t)s0 * DIM + lcol * 4);
                    uint2 u1 = *(const uint2*)(X + (size_t)s1 * DIM + lcol * 4);
                    uint2 u2 = *(const uint2*)(X + (size_t)s2 * DIM + lcol * 4);
                    uint2 u3 = *(const uint2*)(X + (size_t)s3 * DIM + lcol * 4);
                    a0 += bf2f(u0.x & 0xffff) + bf2f(u1.x & 0xffff) + bf2f(u2.x & 0xffff) + bf2f(u3.x & 0xffff);
                    a1 += bf2f(u0.x >> 16)    + bf2f(u1.x >> 16)    + bf2f(u2.x >> 16)    + bf2f(u3.x >> 16);
                    a2 += bf2f(u0.y & 0xffff) + bf2f(u1.y & 0xffff) + bf2f(u2.y & 0xffff) + bf2f(u3.y & 0xffff);
                    a3 += bf2f(u0.y >> 16)    + bf2f(u1.y >> 16)    + bf2f(u2.y >> 16)    + bf2f(u3.y >> 16);
                }
                for (; e < cl; e += 2) {
                    uint2 u0 = *(const uint2*)(X + (size_t)b[e] * DIM + lcol * 4);
                    a0 += bf2f(u0.x & 0xffff);
                    a1 += bf2f(u0.x >> 16);
                    a2 += bf2f(u0.y & 0xffff);
                    a3 += bf2f(u0.y >> 16);
                }
            }
            a0 += __shfl_xor(a0, 32);
            a1 += __shfl_xor(a1, 32);
            a2 += __shfl_xor(a2, 32);
            a3 += __shfl_xor(a3, 32);
            if (half == 0) {
                float inv = 1.0f / (float)(c > 0 ? c : 1);
                uint2 o;
                o.x = ((unsigned int)f2bf(a1 * inv) << 16) | f2bf(a0 * inv);
                o.y = ((unsigned int)f2bf(a3 * inv) << 16) | f2bf(a2 * inv);
                *(uint2*)(&sA[row * LSTR + lcol * 4]) = o;
            }
        }
    }

    // ---- h-part staging (k >= 128), same tensor X ----
    #pragma unroll
    for (int it = 0; it < 2; ++it) {
        int ci = tid + it * 512;        // 0..1023 -> 64 rows x 16 chunks
        int row = ci >> 4;
        int k8 = (ci & 15) * 8;
        int gn = n0 + row;
        bf16x8 v = (bf16x8){0,0,0,0,0,0,0,0};
        if (gn < N_NODES) v = *(const bf16x8*)(X + (size_t)gn * DIM + k8);
        *(bf16x8*)(&sA[row * LSTR + 128 + k8]) = v;
    }

    // W fragments: lane l holds W[jq*32 + (l&31)][kt*16 + (l>>5)*8 .. +7]
    const int mh = w & 1, jq = w >> 1;
    bf16x8 bw[16];
    {
        const ushort* wp = wb + (size_t)(jq * 32 + (lane & 31)) * KTOT + (lane >> 5) * 8;
        #pragma unroll
        for (int kt = 0; kt < 16; ++kt)
            bw[kt] = *(const bf16x8*)(wp + kt * 16);
    }
    __syncthreads();

    f32x16 acc = {};
    const int arow = mh * 32 + (lane & 31);
    const int akoff = (lane >> 5) * 8;
    #pragma unroll
    for (int kt = 0; kt < 16; ++kt) {
        bf16x8 a = *(const bf16x8*)(&sA[arow * LSTR + kt * 16 + akoff]);
        acc = __builtin_amdgcn_mfma_f32_32x32x16_bf16(a, bw[kt], acc, 0, 0, 0);
    }

    // C/D map: col=lane&31, row=(reg&3)+8*(reg>>2)+4*(lane>>5)  [m74/m101]
    const int col = lane & 31;
    const int j = jq * 32 + col;
    const float bias = bl[j];
    #pragma unroll
    for (int r = 0; r < 16; ++r) {
        int row = (r & 3) + 8 * (r >> 2) + 4 * (lane >> 5);
        int gn = n0 + mh * 32 + row;
        if (gn < N_NODES) {
            float v = acc[r] + bias;
            if (relu) v = fmaxf(v, 0.f);
            outb[(size_t)gn * DIM + j] = f2bf(v);
        }
    }
}

// ---------- pool ----------
__global__ void pool1_kernel(const ushort* __restrict__ H, const int* __restrict__ batch,
                             float* __restrict__ pool) {
    const int per = (N_NODES + P_BLOCKS - 1) / P_BLOCKS;
    int n0 = blockIdx.x * per;
    int n1 = n0 + per; if (n1 > N_NODES) n1 = N_NODES;
    if (n0 >= n1) return;
    int j = threadIdx.x;
    float acc = 0.f;
    int g = batch[n0];
    for (int n = n0; n < n1; ++n) {
        int bg = batch[n];
        if (bg != g) {
            unsafeAtomicAdd(&pool[g * DIM + j], acc);
            acc = 0.f; g = bg;
        }
        acc += bf2f(H[(size_t)n * DIM + j]);
    }
    unsafeAtomicAdd(&pool[g * DIM + j], acc);
}

__global__ void pool2_kernel(const float* __restrict__ pool, const int* __restrict__ batch,
                             float* __restrict__ out) {
    int g = blockIdx.x;
    int j = threadIdx.x;
    int lo = 0, hi = N_NODES;
    while (lo < hi) { int m = (lo + hi) >> 1; if (batch[m] < g) lo = m + 1; else hi = m; }
    int start = lo;
    lo = start; hi = N_NODES;
    while (lo < hi) { int m = (lo + hi) >> 1; if (batch[m] < g + 1) lo = m + 1; else hi = m; }
    int cnt = lo - start;
    out[g * DIM + j] = pool[g * DIM + j] / (float)(cnt > 0 ? cnt : 1);
}

extern "C" void kernel_launch(void* const* d_in, const int* in_sizes, int n_in,
                              void* d_out, int out_size, void* d_ws, size_t ws_size,
                              hipStream_t stream) {
    const float* x    = (const float*)d_in[0];
    const int*   ei   = (const int*)d_in[1];
    const int*   src  = ei;
    const int*   dst  = ei + N_EDGES;
    const int*   batch = (const int*)d_in[2];
    const float* Wl0 = (const float*)d_in[3];
    const float* bl0 = (const float*)d_in[4];
    const float* Wr0 = (const float*)d_in[5];
    const float* Wl1 = (const float*)d_in[6];
    const float* bl1 = (const float*)d_in[7];
    const float* Wr1 = (const float*)d_in[8];
    const float* Wl2 = (const float*)d_in[9];
    const float* bl2 = (const float*)d_in[10];
    const float* Wr2 = (const float*)d_in[11];
    float* out = (float*)d_out;

    int*    cnt    = (int*)d_ws;                               // 65536 ints
    ushort* bucket = (ushort*)(cnt + 65536);                   // 3.2M ushorts
    ushort* xb     = bucket + (size_t)N_NODES * BUCKET_CAP;
    ushort* h1b    = xb + (size_t)N_NODES * DIM;
    ushort* h2b    = h1b + (size_t)N_NODES * DIM;
    ushort* h3b    = h2b + (size_t)N_NODES * DIM;
    ushort* wb     = h3b + (size_t)N_NODES * DIM;              // 3 * 32768 bf16
    float*  pool   = (float*)(wb + 3 * DIM * KTOT);            // 8192 floats

    castx_kernel<<<(N_NODES * DIM / 4 + 255) / 256, 256, 0, stream>>>(x, xb, cnt);
    castw_kernel<<<(3 * DIM * KTOT + 255) / 256, 256, 0, stream>>>(Wl0, Wr0, Wl1, Wr1, Wl2, Wr2, wb, pool);
    fill_kernel<<<(N_EDGES + 255) / 256, 256, 0, stream>>>(src, dst, cnt, bucket);

    const int lgrid = (N_NODES + 63) / 64;

    layer_fused<<<lgrid, 512, 0, stream>>>(xb,  wb,         bl0, cnt, bucket, h1b, 1);
    layer_fused<<<lgrid, 512, 0, stream>>>(h1b, wb + 32768, bl1, cnt, bucket, h2b, 1);
    layer_fused<<<lgrid, 512, 0, stream>>>(h2b, wb + 65536, bl2, cnt, bucket, h3b, 0);

    pool1_kernel<<<P_BLOCKS, DIM, 0, stream>>>(h3b, batch, pool);
    pool2_kernel<<<N_GRAPHS, DIM, 0, stream>>>(pool, batch, out);
}

// Round 9
// 381.975 us; speedup vs baseline: 1.6512x; 1.0129x over previous
//
#include <hip/hip_runtime.h>

#define N_NODES 50000
#define N_EDGES 800000
#define DIM 128
#define KTOT 256        // [agg | h] concatenated along k
#define N_GRAPHS 64
#define BUCKET_CAP 64
#define P_BLOCKS 512
#define LSTR 264        // LDS A-tile row stride in bf16 (+8 pad -> conflict-free b128)

typedef __attribute__((ext_vector_type(8))) short bf16x8;
typedef __attribute__((ext_vector_type(16))) float f32x16;

__device__ __forceinline__ float bf2f(unsigned int u16) {
    return __uint_as_float(u16 << 16);
}
__device__ __forceinline__ unsigned short f2bf(float f) {
    unsigned int v = __float_as_uint(f);
    unsigned int r = (v + 0x7fffu + ((v >> 16) & 1u)) >> 16;   // RNE
    return (unsigned short)r;
}

// ---------- setup ----------
// castx also zeros cnt (must precede fill_kernel)
__global__ void castx_kernel(const float* __restrict__ x, ushort* __restrict__ xb,
                             int* __restrict__ cnt) {
    int i = blockIdx.x * blockDim.x + threadIdx.x;
    if (i < N_NODES) cnt[i] = 0;
    if (i >= N_NODES * DIM / 4) return;
    float4 v = ((const float4*)x)[i];
    ushort4 o;
    o.x = f2bf(v.x); o.y = f2bf(v.y); o.z = f2bf(v.z); o.w = f2bf(v.w);
    ((ushort4*)xb)[i] = o;
}

// wb layout per layer: [128 j][256 k] with k<128 = Wl, k>=128 = Wr. Also zeros pool.
__global__ void castw_kernel(const float* __restrict__ Wl0, const float* __restrict__ Wr0,
                             const float* __restrict__ Wl1, const float* __restrict__ Wr1,
                             const float* __restrict__ Wl2, const float* __restrict__ Wr2,
                             ushort* __restrict__ wb, float* __restrict__ pool) {
    int id = blockIdx.x * blockDim.x + threadIdx.x;
    if (id < N_GRAPHS * DIM) pool[id] = 0.f;
    if (id >= 3 * DIM * KTOT) return;
    int l = id >> 15;
    int r = id & 32767;
    int j = r >> 8, k = r & 255;
    const float* Wl = (l == 0) ? Wl0 : (l == 1) ? Wl1 : Wl2;
    const float* Wr = (l == 0) ? Wr0 : (l == 1) ? Wr1 : Wr2;
    float v = (k < DIM) ? Wl[j * DIM + k] : Wr[j * DIM + k - DIM];
    wb[id] = f2bf(v);
}

// ushort buckets: src < 50000 fits 16 bits (R6-proven; CSR+scan regressed in R7).
__global__ void fill_kernel(const int* __restrict__ src, const int* __restrict__ dst,
                            int* __restrict__ cnt, ushort* __restrict__ bucket) {
    int e = blockIdx.x * blockDim.x + threadIdx.x;
    if (e >= N_EDGES) return;
    int d = dst[e];
    int pos = atomicAdd(&cnt[d], 1);
    if (pos < BUCKET_CAP) bucket[d * BUCKET_CAP + pos] = (ushort)src[e];
}

// ---------- fused layer: gather (mean-agg into LDS) + MFMA GEMM ----------
// out[n][:] = act( [mean_agg(X)[n] | X[n]] @ W^T + bl ),  W = [Wl|Wr] 128x256.
// 512 thr = 8 waves, 64 nodes/block. launch_bounds(512,8): 2nd arg is waves/EU;
// 8 -> 4 blocks/CU (LDS-limited: 4x33.8KB of 160KB), 32 waves/CU. R8's (512,2)
// capped us at 1 block/CU = 30% occupancy — the gather is latency-bound and
// needs the wave slots.
__global__ __launch_bounds__(512, 8) void layer_fused(
    const ushort* __restrict__ X, const ushort* __restrict__ wb,
    const float* __restrict__ bl, const int* __restrict__ cnt,
    const ushort* __restrict__ bucket, ushort* __restrict__ outb, int relu)
{
    __shared__ ushort sA[64 * LSTR];
    const int tid = threadIdx.x;
    const int lane = tid & 63, w = tid >> 6;
    const int n0 = blockIdx.x * 64;
    const int mh = w & 1, jq = w >> 1;

    // W fragments first: 16 independent global loads issue before the gather
    // chain; lane l holds W[jq*32 + (l&31)][kt*16 + (l>>5)*8 .. +7]
    bf16x8 bw[16];
    {
        const ushort* wp = wb + (size_t)(jq * 32 + (lane & 31)) * KTOT + (lane >> 5) * 8;
        #pragma unroll
        for (int kt = 0; kt < 16; ++kt)
            bw[kt] = *(const bf16x8*)(wp + kt * 16);
    }

    // ---- gather phase: wave w owns rows w*8..w*8+7 ----
    {
        const int half = lane >> 5;      // 0/1: even/odd edges
        const int lcol = lane & 31;      // 4 cols (8 B) of the 256 B row
        for (int i = 0; i < 8; ++i) {
            int row = w * 8 + i;
            int gn = n0 + row;
            float a0 = 0.f, a1 = 0.f, a2 = 0.f, a3 = 0.f;
            int c = 0;
            if (gn < N_NODES) {
                c = cnt[gn];
                int cl = c < BUCKET_CAP ? c : BUCKET_CAP;
                const ushort* b = bucket + (size_t)gn * BUCKET_CAP;
                int e = half;
                for (; e + 6 < cl; e += 8) {
                    int s0 = b[e], s1 = b[e + 2], s2 = b[e + 4], s3 = b[e + 6];
                    uint2 u0 = *(const uint2*)(X + (size_t)s0 * DIM + lcol * 4);
                    uint2 u1 = *(const uint2*)(X + (size_t)s1 * DIM + lcol * 4);
                    uint2 u2 = *(const uint2*)(X + (size_t)s2 * DIM + lcol * 4);
                    uint2 u3 = *(const uint2*)(X + (size_t)s3 * DIM + lcol * 4);
                    a0 += bf2f(u0.x & 0xffff) + bf2f(u1.x & 0xffff) + bf2f(u2.x & 0xffff) + bf2f(u3.x & 0xffff);
                    a1 += bf2f(u0.x >> 16)    + bf2f(u1.x >> 16)    + bf2f(u2.x >> 16)    + bf2f(u3.x >> 16);
                    a2 += bf2f(u0.y & 0xffff) + bf2f(u1.y & 0xffff) + bf2f(u2.y & 0xffff) + bf2f(u3.y & 0xffff);
                    a3 += bf2f(u0.y >> 16)    + bf2f(u1.y >> 16)    + bf2f(u2.y >> 16)    + bf2f(u3.y >> 16);
                }
                for (; e < cl; e += 2) {
                    uint2 u0 = *(const uint2*)(X + (size_t)b[e] * DIM + lcol * 4);
                    a0 += bf2f(u0.x & 0xffff);
                    a1 += bf2f(u0.x >> 16);
                    a2 += bf2f(u0.y & 0xffff);
                    a3 += bf2f(u0.y >> 16);
                }
            }
            a0 += __shfl_xor(a0, 32);
            a1 += __shfl_xor(a1, 32);
            a2 += __shfl_xor(a2, 32);
            a3 += __shfl_xor(a3, 32);
            if (half == 0) {
                float inv = 1.0f / (float)(c > 0 ? c : 1);
                uint2 o;
                o.x = ((unsigned int)f2bf(a1 * inv) << 16) | f2bf(a0 * inv);
                o.y = ((unsigned int)f2bf(a3 * inv) << 16) | f2bf(a2 * inv);
                *(uint2*)(&sA[row * LSTR + lcol * 4]) = o;
            }
        }
    }

    // ---- h-part staging (k >= 128), same tensor X ----
    #pragma unroll
    for (int it = 0; it < 2; ++it) {
        int ci = tid + it * 512;        // 0..1023 -> 64 rows x 16 chunks
        int row = ci >> 4;
        int k8 = (ci & 15) * 8;
        int gn = n0 + row;
        bf16x8 v = (bf16x8){0,0,0,0,0,0,0,0};
        if (gn < N_NODES) v = *(const bf16x8*)(X + (size_t)gn * DIM + k8);
        *(bf16x8*)(&sA[row * LSTR + 128 + k8]) = v;
    }
    __syncthreads();

    f32x16 acc = {};
    const int arow = mh * 32 + (lane & 31);
    const int akoff = (lane >> 5) * 8;
    #pragma unroll
    for (int kt = 0; kt < 16; ++kt) {
        bf16x8 a = *(const bf16x8*)(&sA[arow * LSTR + kt * 16 + akoff]);
        acc = __builtin_amdgcn_mfma_f32_32x32x16_bf16(a, bw[kt], acc, 0, 0, 0);
    }

    // C/D map: col=lane&31, row=(reg&3)+8*(reg>>2)+4*(lane>>5)  [m74/m101]
    const int col = lane & 31;
    const int j = jq * 32 + col;
    const float bias = bl[j];
    #pragma unroll
    for (int r = 0; r < 16; ++r) {
        int row = (r & 3) + 8 * (r >> 2) + 4 * (lane >> 5);
        int gn = n0 + mh * 32 + row;
        if (gn < N_NODES) {
            float v = acc[r] + bias;
            if (relu) v = fmaxf(v, 0.f);
            outb[(size_t)gn * DIM + j] = f2bf(v);
        }
    }
}

// ---------- pool ----------
__global__ void pool1_kernel(const ushort* __restrict__ H, const int* __restrict__ batch,
                             float* __restrict__ pool) {
    const int per = (N_NODES + P_BLOCKS - 1) / P_BLOCKS;
    int n0 = blockIdx.x * per;
    int n1 = n0 + per; if (n1 > N_NODES) n1 = N_NODES;
    if (n0 >= n1) return;
    int j = threadIdx.x;
    float acc = 0.f;
    int g = batch[n0];
    for (int n = n0; n < n1; ++n) {
        int bg = batch[n];
        if (bg != g) {
            unsafeAtomicAdd(&pool[g * DIM + j], acc);
            acc = 0.f; g = bg;
        }
        acc += bf2f(H[(size_t)n * DIM + j]);
    }
    unsafeAtomicAdd(&pool[g * DIM + j], acc);
}

__global__ void pool2_kernel(const float* __restrict__ pool, const int* __restrict__ batch,
                             float* __restrict__ out) {
    int g = blockIdx.x;
    int j = threadIdx.x;
    int lo = 0, hi = N_NODES;
    while (lo < hi) { int m = (lo + hi) >> 1; if (batch[m] < g) lo = m + 1; else hi = m; }
    int start = lo;
    lo = start; hi = N_NODES;
    while (lo < hi) { int m = (lo + hi) >> 1; if (batch[m] < g + 1) lo = m + 1; else hi = m; }
    int cnt = lo - start;
    out[g * DIM + j] = pool[g * DIM + j] / (float)(cnt > 0 ? cnt : 1);
}

extern "C" void kernel_launch(void* const* d_in, const int* in_sizes, int n_in,
                              void* d_out, int out_size, void* d_ws, size_t ws_size,
                              hipStream_t stream) {
    const float* x    = (const float*)d_in[0];
    const int*   ei   = (const int*)d_in[1];
    const int*   src  = ei;
    const int*   dst  = ei + N_EDGES;
    const int*   batch = (const int*)d_in[2];
    const float* Wl0 = (const float*)d_in[3];
    const float* bl0 = (const float*)d_in[4];
    const float* Wr0 = (const float*)d_in[5];
    const float* Wl1 = (const float*)d_in[6];
    const float* bl1 = (const float*)d_in[7];
    const float* Wr1 = (const float*)d_in[8];
    const float* Wl2 = (const float*)d_in[9];
    const float* bl2 = (const float*)d_in[10];
    const float* Wr2 = (const float*)d_in[11];
    float* out = (float*)d_out;

    int*    cnt    = (int*)d_ws;                               // 65536 ints
    ushort* bucket = (ushort*)(cnt + 65536);                   // 3.2M ushorts
    ushort* xb     = bucket + (size_t)N_NODES * BUCKET_CAP;
    ushort* h1b    = xb + (size_t)N_NODES * DIM;
    ushort* h2b    = h1b + (size_t)N_NODES * DIM;
    ushort* h3b    = h2b + (size_t)N_NODES * DIM;
    ushort* wb     = h3b + (size_t)N_NODES * DIM;              // 3 * 32768 bf16
    float*  pool   = (float*)(wb + 3 * DIM * KTOT);            // 8192 floats

    castx_kernel<<<(N_NODES * DIM / 4 + 255) / 256, 256, 0, stream>>>(x, xb, cnt);
    castw_kernel<<<(3 * DIM * KTOT + 255) / 256, 256, 0, stream>>>(Wl0, Wr0, Wl1, Wr1, Wl2, Wr2, wb, pool);
    fill_kernel<<<(N_EDGES + 255) / 256, 256, 0, stream>>>(src, dst, cnt, bucket);

    const int lgrid = (N_NODES + 63) / 64;

    layer_fused<<<lgrid, 512, 0, stream>>>(xb,  wb,         bl0, cnt, bucket, h1b, 1);
    layer_fused<<<lgrid, 512, 0, stream>>>(h1b, wb + 32768, bl1, cnt, bucket, h2b, 1);
    layer_fused<<<lgrid, 512, 0, stream>>>(h2b, wb + 65536, bl2, cnt, bucket, h3b, 0);

    pool1_kernel<<<P_BLOCKS, DIM, 0, stream>>>(h3b, batch, pool);
    pool2_kernel<<<N_GRAPHS, DIM, 0, stream>>>(pool, batch, out);
}